// Round 1
// baseline (2873.760 us; speedup 1.0000x reference)
//
#include <hip/hip_runtime.h>
#include <math.h>

// SpeMamba encoder: B=16, L=512, EMB=256, TOKEN_NUM=8, GC=32, DI=64, DS=16,
// DCONV=4, DTR=2, GN_GROUPS=4, LAYERS=4.
// Layout: h kept as [B, L, 256] (== final output layout). Position n = b*512+l.
// u[t][c] = h[n*256 + t*32 + c].

#define NPOS   8192
#define NWAVE1 4096   // waves in k_mamba (1024 blocks * 4 waves)

__device__ __forceinline__ float sigf(float v)   { return 1.0f / (1.0f + __expf(-v)); }
__device__ __forceinline__ float siluf(float v)  { return v * sigf(v); }
__device__ __forceinline__ float softplusf(float v) { return (v > 20.0f) ? v : log1pf(__expf(v)); }

// One wave = one position. Lane = d_inner channel (0..63).
// LDS: Wi [128][33] (2-way free), Wx [34][68] (conflict-free for lane->(fi,tt) map),
// WoT [64][36] (conflict-free for lane->(t,c4) map), per-wave scratch 864 floats.
__global__ __launch_bounds__(256, 3)
void k_mamba(const float* __restrict__ hin, float* __restrict__ xr,
             const float* __restrict__ Wi_g, const float* __restrict__ Wc_g,
             const float* __restrict__ bc_g, const float* __restrict__ Wx_g,
             const float* __restrict__ Wdt_g, const float* __restrict__ bdt_g,
             const float* __restrict__ Alog_g, const float* __restrict__ D_g,
             const float* __restrict__ Wo_g)
{
    __shared__ __align__(16) float sm[12296];
    float* const sWi  = sm;          // [128][33] = 4224
    float* const sWx  = sm + 4224;   // [34][68]  = 2312
    float* const sWoT = sm + 6536;   // [64][36]  = 2304  (WoT[e][c])
    float* const sScr = sm + 8840;   // 4 waves * 864

    const int tid = threadIdx.x;
    for (int i = tid; i < 128*32; i += 256) sWi[(i >> 5)*33 + (i & 31)] = Wi_g[i];
    for (int i = tid; i < 34*64;  i += 256) sWx[(i >> 6)*68 + (i & 63)] = Wx_g[i];
    for (int i = tid; i < 32*64;  i += 256) sWoT[(i & 63)*36 + (i >> 6)] = Wo_g[i];

    const int wav = tid >> 6;
    const int ln  = tid & 63;
    float* const xb   = sScr + wav*864;         // [8][68] x-tile (aliased by yb)
    float* const xdbl = sScr + wav*864 + 544;   // [8][40]: [B 0..15 | C 16..31 | dt 32..33]
    float* const ubuf = xdbl;                   // [8][32] alias (u dead before xdbl written)
    float* const yb   = xb;                     // alias   (xb dead before yb written)

    // lane-private constants (loaded once; global, L1/L2-cached)
    const float4 cw4 = *(const float4*)(Wc_g + ln*4);
    const float  cb   = bc_g[ln];
    const float  wdt0 = Wdt_g[ln*2 + 0];
    const float  wdt1 = Wdt_g[ln*2 + 1];
    const float  bdt  = bdt_g[ln];
    const float  Dd   = D_g[ln];
    float a[16];
    {
        const float4* Ar = (const float4*)(Alog_g + ln*16);
        #pragma unroll
        for (int q = 0; q < 4; ++q) {
            float4 v = Ar[q];
            a[q*4+0] = -__expf(v.x); a[q*4+1] = -__expf(v.y);
            a[q*4+2] = -__expf(v.z); a[q*4+3] = -__expf(v.w);
        }
    }
    __syncthreads();

    const int gw = blockIdx.x*4 + wav;
    #pragma unroll 1
    for (int it = 0; it < 2; ++it) {
        const int p = gw + it*NWAVE1;

        // stage u (256 consecutive floats, coalesced)
        *(float4*)(ubuf + ln*4) = *(const float4*)(hin + (size_t)p*256 + ln*4);
        __syncthreads();

        // ---- in_proj: x[t] = sum_c u[t,c]*Wi[d,c];  z[t] = sum_c u[t,c]*Wi[64+d,c]
        float x[8], z[8];
        #pragma unroll
        for (int t = 0; t < 8; ++t) { x[t] = 0.f; z[t] = 0.f; }
        #pragma unroll
        for (int c0 = 0; c0 < 32; c0 += 4) {
            const float wx0 = sWi[ln*33 + c0+0], wx1 = sWi[ln*33 + c0+1];
            const float wx2 = sWi[ln*33 + c0+2], wx3 = sWi[ln*33 + c0+3];
            const float wz0 = sWi[(64+ln)*33 + c0+0], wz1 = sWi[(64+ln)*33 + c0+1];
            const float wz2 = sWi[(64+ln)*33 + c0+2], wz3 = sWi[(64+ln)*33 + c0+3];
            #pragma unroll
            for (int t = 0; t < 8; ++t) {
                const float4 u4 = *(const float4*)(ubuf + t*32 + c0);
                x[t] = fmaf(u4.x, wx0, fmaf(u4.y, wx1, fmaf(u4.z, wx2, fmaf(u4.w, wx3, x[t]))));
                z[t] = fmaf(u4.x, wz0, fmaf(u4.y, wz1, fmaf(u4.z, wz2, fmaf(u4.w, wz3, z[t]))));
            }
        }

        // ---- causal depthwise conv (k=4, left pad 3) + bias + silu
        {
            float xp[11];
            xp[0] = 0.f; xp[1] = 0.f; xp[2] = 0.f;
            #pragma unroll
            for (int t = 0; t < 8; ++t) xp[t+3] = x[t];
            #pragma unroll
            for (int t = 0; t < 8; ++t) {
                float v = cb;
                v = fmaf(cw4.x, xp[t+0], v);
                v = fmaf(cw4.y, xp[t+1], v);
                v = fmaf(cw4.z, xp[t+2], v);
                v = fmaf(cw4.w, xp[t+3], v);
                x[t] = siluf(v);
            }
        }

        // ---- stash x for cross-lane x_proj
        #pragma unroll
        for (int t = 0; t < 8; ++t) xb[t*68 + ln] = x[t];
        __syncthreads();

        // ---- x_proj: xdbl[t,f] = sum_e x[t,e]*Wx[f,e]; lane -> (fi = ln>>3, tt = ln&7)
        {
            const int fi = ln >> 3, tt = ln & 7;
            float p0 = 0.f, p1 = 0.f, p2 = 0.f, p3 = 0.f, p4 = 0.f;
            #pragma unroll
            for (int e = 0; e < 64; e += 4) {
                const float4 x4 = *(const float4*)(xb + tt*68 + e);
                float4 w;
                w = *(const float4*)(sWx + (fi)*68 + e);
                p0 += x4.x*w.x + x4.y*w.y + x4.z*w.z + x4.w*w.w;
                w = *(const float4*)(sWx + (8+fi)*68 + e);
                p1 += x4.x*w.x + x4.y*w.y + x4.z*w.z + x4.w*w.w;
                w = *(const float4*)(sWx + (16+fi)*68 + e);
                p2 += x4.x*w.x + x4.y*w.y + x4.z*w.z + x4.w*w.w;
                w = *(const float4*)(sWx + (24+fi)*68 + e);
                p3 += x4.x*w.x + x4.y*w.y + x4.z*w.z + x4.w*w.w;
                if (fi < 2) {
                    w = *(const float4*)(sWx + (32+fi)*68 + e);
                    p4 += x4.x*w.x + x4.y*w.y + x4.z*w.z + x4.w*w.w;
                }
            }
            // slot(f): f<2 -> 32+f (dt), else f-2 (B: 0..15, C: 16..31)
            xdbl[tt*40 + ((fi < 2) ? (32 + fi) : (fi - 2))] = p0;
            xdbl[tt*40 + 6  + fi] = p1;
            xdbl[tt*40 + 14 + fi] = p2;
            xdbl[tt*40 + 22 + fi] = p3;
            if (fi < 2) xdbl[tt*40 + 30 + fi] = p4;
        }
        __syncthreads();

        // ---- dt_proj + softplus + selective scan + gate
        {
            float hs[16];
            #pragma unroll
            for (int s = 0; s < 16; ++s) hs[s] = 0.f;
            #pragma unroll
            for (int t = 0; t < 8; ++t) {
                const float d0  = xdbl[t*40 + 32];
                const float d1  = xdbl[t*40 + 33];
                const float del = softplusf(fmaf(d0, wdt0, fmaf(d1, wdt1, bdt)));
                const float dx  = del * x[t];
                float y = 0.f;
                #pragma unroll
                for (int q = 0; q < 4; ++q) {
                    const float4 B4 = *(const float4*)(xdbl + t*40 + q*4);
                    const float4 C4 = *(const float4*)(xdbl + t*40 + 16 + q*4);
                    float dA;
                    dA = __expf(del * a[q*4+0]); hs[q*4+0] = fmaf(dA, hs[q*4+0], dx*B4.x); y = fmaf(hs[q*4+0], C4.x, y);
                    dA = __expf(del * a[q*4+1]); hs[q*4+1] = fmaf(dA, hs[q*4+1], dx*B4.y); y = fmaf(hs[q*4+1], C4.y, y);
                    dA = __expf(del * a[q*4+2]); hs[q*4+2] = fmaf(dA, hs[q*4+2], dx*B4.z); y = fmaf(hs[q*4+2], C4.z, y);
                    dA = __expf(del * a[q*4+3]); hs[q*4+3] = fmaf(dA, hs[q*4+3], dx*B4.w); y = fmaf(hs[q*4+3], C4.w, y);
                }
                y = fmaf(x[t], Dd, y);
                y *= siluf(z[t]);
                yb[t*68 + ln] = y;   // yb aliases xb; xb LDS last read in x_proj (barrier above)
            }
        }
        __syncthreads();

        // ---- out_proj: out[t,c] = sum_e y[t,e]*Wo[c,e]; lane -> (t = ln>>3, c4 = (ln&7)*4)
        {
            const int gt = ln >> 3;
            const int c4 = (ln & 7) * 4;
            float o0 = 0.f, o1 = 0.f, o2 = 0.f, o3 = 0.f;
            #pragma unroll
            for (int e0 = 0; e0 < 64; e0 += 4) {
                const float4 y4 = *(const float4*)(yb + gt*68 + e0);
                float4 w;
                w = *(const float4*)(sWoT + (e0+0)*36 + c4);
                o0 = fmaf(y4.x, w.x, o0); o1 = fmaf(y4.x, w.y, o1);
                o2 = fmaf(y4.x, w.z, o2); o3 = fmaf(y4.x, w.w, o3);
                w = *(const float4*)(sWoT + (e0+1)*36 + c4);
                o0 = fmaf(y4.y, w.x, o0); o1 = fmaf(y4.y, w.y, o1);
                o2 = fmaf(y4.y, w.z, o2); o3 = fmaf(y4.y, w.w, o3);
                w = *(const float4*)(sWoT + (e0+2)*36 + c4);
                o0 = fmaf(y4.z, w.x, o0); o1 = fmaf(y4.z, w.y, o1);
                o2 = fmaf(y4.z, w.z, o2); o3 = fmaf(y4.z, w.w, o3);
                w = *(const float4*)(sWoT + (e0+3)*36 + c4);
                o0 = fmaf(y4.w, w.x, o0); o1 = fmaf(y4.w, w.y, o1);
                o2 = fmaf(y4.w, w.z, o2); o3 = fmaf(y4.w, w.w, o3);
            }
            float4 o; o.x = o0; o.y = o1; o.z = o2; o.w = o3;
            *(float4*)(xr + (size_t)p*256 + gt*32 + c4) = o;   // lanes cover n*256..n*256+255
        }
        // no trailing barrier needed: all scratch is wave-private; loop-top barrier re-syncs
    }
}

// GroupNorm stats: one block per (b, g); reduce 512 positions x 64 channels.
__global__ void k_gnstats(const float* __restrict__ xr, float* __restrict__ stats)
{
    const int b = blockIdx.x >> 2, g = blockIdx.x & 3;
    const int tid = threadIdx.x;
    const float* base = xr + (size_t)b*512*256 + g*64;
    float s = 0.f, ss = 0.f;
    for (int i = tid; i < 512*16; i += 256) {
        const int l = i >> 4, c4 = (i & 15) * 4;
        const float4 v = *(const float4*)(base + (size_t)l*256 + c4);
        s  += v.x + v.y + v.z + v.w;
        ss += v.x*v.x + v.y*v.y + v.z*v.z + v.w*v.w;
    }
    __shared__ float rs[256], rss[256];
    rs[tid] = s; rss[tid] = ss;
    __syncthreads();
    for (int off = 128; off > 0; off >>= 1) {
        if (tid < off) { rs[tid] += rs[tid+off]; rss[tid] += rss[tid+off]; }
        __syncthreads();
    }
    if (tid == 0) {
        const float mu  = rs[0] * (1.f/32768.f);
        const float var = rss[0] * (1.f/32768.f) - mu*mu;
        stats[blockIdx.x*2 + 0] = mu;
        stats[blockIdx.x*2 + 1] = rsqrtf(var + 1e-5f);
    }
}

// h_out = h_in + silu(gn(xr)); 4 elements per thread, float4.
__global__ void k_gnapply(const float* __restrict__ hin, const float* __restrict__ xrb,
                          const float* __restrict__ stats, const float* __restrict__ gamma,
                          const float* __restrict__ beta, float* __restrict__ hout)
{
    const int idx = blockIdx.x*256 + threadIdx.x;   // 0..524287
    const int e = idx * 4;
    const int c = e & 255;
    const int n = idx >> 6;     // position
    const int b = n >> 9;
    const int g = c >> 6;
    const float mu   = stats[(b*4+g)*2 + 0];
    const float rstd = stats[(b*4+g)*2 + 1];
    const float4 xv = *(const float4*)(xrb + e);
    float4 hv = *(const float4*)(hin + e);
    const float4 gm = *(const float4*)(gamma + c);
    const float4 bt = *(const float4*)(beta + c);
    hv.x += siluf(fmaf((xv.x - mu)*rstd, gm.x, bt.x));
    hv.y += siluf(fmaf((xv.y - mu)*rstd, gm.y, bt.y));
    hv.z += siluf(fmaf((xv.z - mu)*rstd, gm.z, bt.z));
    hv.w += siluf(fmaf((xv.w - mu)*rstd, gm.w, bt.w));
    *(float4*)(hout + e) = hv;
}

extern "C" void kernel_launch(void* const* d_in, const int* in_sizes, int n_in,
                              void* d_out, int out_size, void* d_ws, size_t ws_size,
                              hipStream_t stream)
{
    const float* x    = (const float*)d_in[0];
    const float* Wi   = (const float*)d_in[1];
    const float* Wc   = (const float*)d_in[2];
    const float* bc   = (const float*)d_in[3];
    const float* Wx   = (const float*)d_in[4];
    const float* Wdt  = (const float*)d_in[5];
    const float* bdt  = (const float*)d_in[6];
    const float* Alog = (const float*)d_in[7];
    const float* Dp   = (const float*)d_in[8];
    const float* Wo   = (const float*)d_in[9];
    const float* gam  = (const float*)d_in[10];
    const float* bet  = (const float*)d_in[11];

    float* out   = (float*)d_out;          // running h buffer ([B,L,256]); final result lands here
    float* xrb   = (float*)d_ws;           // 2,097,152 floats: mamba output per layer
    float* stats = xrb + 2097152;          // 128 floats: (mu, rstd) per (b, g)

    for (int layer = 0; layer < 4; ++layer) {
        const float* hi = (layer == 0) ? x : out;
        k_mamba<<<1024, 256, 0, stream>>>(hi, xrb,
            Wi + layer*4096, Wc + layer*256, bc + layer*64,
            Wx + layer*2176, Wdt + layer*128, bdt + layer*64,
            Alog + layer*1024, Dp + layer*64, Wo + layer*2048);
        k_gnstats<<<64, 256, 0, stream>>>(xrb, stats);
        k_gnapply<<<2048, 256, 0, stream>>>(hi, xrb, stats,
            gam + layer*256, bet + layer*256, out);
    }
}